// Round 14
// baseline (114.744 us; speedup 1.0000x reference)
//
#include <hip/hip_runtime.h>
#include <hip/hip_bf16.h>
#include <math.h>

#define EPSV 1e-5f
#define HD   128
#define WROW 40   // Wt bf16 row stride: 80B = 5 quartets, gcd(5,8)=1 -> balanced

typedef __attribute__((ext_vector_type(8))) short bf16x8;   // 8 bf16 = 4 VGPRs
typedef __attribute__((ext_vector_type(4))) float f32x4;

static __device__ __forceinline__ unsigned int bfbits(float x) {
    __hip_bfloat16 h = __float2bfloat16(x);
    unsigned short u;
    __builtin_memcpy(&u, &h, 2);
    return (unsigned int)u;
}

// One block per (b,t). blockDim = 256 = ND. 4 waves. Single dispatch.
// R14 = R13 + split-K-2 tail GEMVs with all 256 threads, same 5 barriers:
// partials merge via ds_add_f32 into h1pre[j] (pre-init b1) / outred[j]
// (pre-init b2); layer-2 applies leaky on-read. Halves each thread's serial
// tail L2-load chain (128 -> 64) and stops waves 2-3 idling through the tail
// (R13 evidence: layer-0 MFMA halving bought only ~2.5us -> tail was the
// remaining per-block critical path).
// KEEP __launch_bounds__(256,4): (256,6) makes the allocator clamp to 40
// VGPR and spill MFMA operands to scratch (R11/R12: FETCH 62MB, WRITE 119MB).
// Numerics (verified R12/R13, absmax 0.0078): A-side lo compensation dropped
// (varying-feature bf16 noise averages over 256 pooled particles); W-side
// compensation free (B rows [whi k0..8|wlo k16..24], A-hi duplicated in both
// halves => ONE mfma = ahi*(whi+wlo)); constant features (W0 rows 4..13)
// exact fp32 via cvec folded into the MFMA accumulator init.
__global__ __launch_bounds__(256, 4) void net_fused(
    const float* __restrict__ x0g, const float* __restrict__ xg,
    const int*   __restrict__ Ng,  const float* __restrict__ basisg,
    const float* __restrict__ vg,  const float* __restrict__ Pg,
    const float* __restrict__ W0,  const float* __restrict__ b0,
    const float* __restrict__ W1,  const float* __restrict__ b1,
    const float* __restrict__ W2,  const float* __restrict__ b2,
    float* __restrict__ out, int Tn, int NDn)
{
    __shared__ __align__(16) __hip_bfloat16 Wt[128 * WROW];  // [whi|wlo] rows
    __shared__ float cvec[HD];        // exact constant-feature contribution
    __shared__ float hvec[HD];        // pooled (atomic-accumulated) + logN
    __shared__ float h1pre[HD];       // layer-1 pre-activation (atomic)
    __shared__ float outred[HD];      // layer-2 accumulation (atomic)
    __shared__ float vred[4][3];      // v-mean wave partials

    const int bt   = blockIdx.x;
    const int b    = bt / Tn;
    const int tid  = threadIdx.x;
    const int lane = tid & 63;
    const int wave = tid >> 6;
    const int quad = lane >> 4;
    const int lm   = lane & 15;

    // ---- per-particle global loads (particle i = tid) ----
    const long pbase = ((long)bt * NDn + tid) * 3;
    const float xi0 = xg[pbase+0], xi1 = xg[pbase+1], xi2 = xg[pbase+2];
    const float vi0 = vg[pbase+0], vi1 = vg[pbase+1], vi2 = vg[pbase+2];

    // ---- v0 mean: wave shuffle reduce -> vred ----
    float s0 = vi0, s1 = vi1, s2 = vi2;
    #pragma unroll
    for (int off = 32; off > 0; off >>= 1) {
        s0 += __shfl_down(s0, off);
        s1 += __shfl_down(s1, off);
        s2 += __shfl_down(s2, off);
    }
    if (lane == 0) { vred[wave][0] = s0; vred[wave][1] = s1; vred[wave][2] = s2; }

    // ---- Wt staging by threads 0..127: row n = [whi k0..8 | wlo k16..24] ----
    if (tid < 128) {
        const int RV[9] = {0, 1, 2, 3, 14, 15, 16, 17, 18};
        __hip_bfloat16 r1[32];
        #pragma unroll
        for (int kk = 0; kk < 32; ++kk) r1[kk] = __float2bfloat16(0.0f);
        if (tid < 127) {
            #pragma unroll
            for (int kk = 0; kk < 9; ++kk) {
                const float wv = W0[RV[kk] * 127 + tid];   // coalesced across tid
                const __hip_bfloat16 hi = __float2bfloat16(wv);
                r1[kk]      = hi;                                          // whi
                r1[16 + kk] = __float2bfloat16(wv - __bfloat162float(hi)); // wlo
            }
        }
        bf16x8* d1 = reinterpret_cast<bf16x8*>(&Wt[tid * WROW]);
        const bf16x8* s1v = reinterpret_cast<const bf16x8*>(r1);
        d1[0] = s1v[0]; d1[1] = s1v[1]; d1[2] = s1v[2]; d1[3] = s1v[3];
    }
    __syncthreads();                                             // B1

    const float inv_nd = 1.0f / (float)NDn;
    const float v00 = (vred[0][0]+vred[1][0]+vred[2][0]+vred[3][0]) * inv_nd;
    const float v01 = (vred[0][1]+vred[1][1]+vred[2][1]+vred[3][1]) * inv_nd;
    const float v02 = (vred[0][2]+vred[1][2]+vred[2][2]+vred[3][2]) * inv_nd;

    // ---- per-(b,t) scalars ----
    const float p0 = x0g[bt*3+0], p1 = x0g[bt*3+1], p2 = x0g[bt*3+2];
    float bas[3][3];
    #pragma unroll
    for (int k = 0; k < 3; ++k)
        #pragma unroll
        for (int c = 0; c < 3; ++c)
            bas[k][c] = basisg[(b*3 + k)*3 + c];

    const float x0n  = sqrtf(p0*p0 + p1*p1 + p2*p2) + EPSV;
    const float ix0n = 1.0f / x0n;
    const float x0u0 = p0*ix0n, x0u1 = p1*ix0n, x0u2 = p2*ix0n;

    const float v0n  = sqrtf(v00*v00 + v01*v01 + v02*v02) + EPSV;
    const float iv0n = 1.0f / v0n;
    const float v0u0 = v00*iv0n, v0u1 = v01*iv0n, v0u2 = v02*iv0n;

    const float logN = log1pf((float)Ng[bt]);

    // ---- exact fp32 constant-feature contribution + accumulator inits ----
    if (tid < 128) {
        float c = 0.0f;
        if (tid < 127) {
            float fc[10];
            fc[0] = logN;
            fc[1] = x0n;
            fc[2] = x0u0*bas[0][0] + x0u1*bas[0][1] + x0u2*bas[0][2];
            fc[3] = x0u0*bas[1][0] + x0u1*bas[1][1] + x0u2*bas[1][2];
            fc[4] = x0u0*bas[2][0] + x0u1*bas[2][1] + x0u2*bas[2][2];
            fc[5] = v0n;
            fc[6] = v0u0*bas[0][0] + v0u1*bas[0][1] + v0u2*bas[0][2];
            fc[7] = v0u0*bas[1][0] + v0u1*bas[1][1] + v0u2*bas[1][2];
            fc[8] = v0u0*bas[2][0] + v0u1*bas[2][1] + v0u2*bas[2][2];
            fc[9] = x0u0*v0u0 + x0u1*v0u1 + x0u2*v0u2;
            c = b0[tid];
            #pragma unroll
            for (int i = 0; i < 10; ++i)
                c = fmaf(fc[i], W0[(4 + i) * 127 + tid], c);
        }
        cvec[tid]   = c;
        hvec[tid]   = (tid == 127) ? logN : 0.0f;   // pool base
        h1pre[tid]  = b1[tid];                      // layer-1 atomic base
        outred[tid] = b2[tid];                      // layer-2 atomic base
    }

    // ---- varying features -> packed bf16-hi registers H[5] (no LDS, no lo) ----
    unsigned int H[5];
    {
        const float xn  = sqrtf(xi0*xi0 + xi1*xi1 + xi2*xi2) + EPSV;
        const float ixn = 1.0f / xn;
        const float xu0 = xi0*ixn, xu1 = xi1*ixn, xu2 = xi2*ixn;

        const float c0 = vi0 - v00, c1 = vi1 - v01, c2 = vi2 - v02;
        const float vn  = sqrtf(c0*c0 + c1*c1 + c2*c2) + EPSV;
        const float ivn = 1.0f / vn;
        const float vu0 = c0*ivn, vu1 = c1*ivn, vu2 = c2*ivn;

        float f[9];
        f[0] = xn;                                            // W0 row 0
        f[1] = xu0*bas[0][0] + xu1*bas[0][1] + xu2*bas[0][2]; // row 1
        f[2] = xu0*bas[1][0] + xu1*bas[1][1] + xu2*bas[1][2]; // row 2
        f[3] = xu0*bas[2][0] + xu1*bas[2][1] + xu2*bas[2][2]; // row 3
        f[4] = vn;                                            // row 14
        f[5] = vu0*bas[0][0] + vu1*bas[0][1] + vu2*bas[0][2]; // row 15
        f[6] = vu0*bas[1][0] + vu1*bas[1][1] + vu2*bas[1][2]; // row 16
        f[7] = vu0*bas[2][0] + vu1*bas[2][1] + vu2*bas[2][2]; // row 17
        f[8] = xu0*vu0 + xu1*vu1 + xu2*vu2;                   // row 18

        unsigned int hb[9];
        #pragma unroll
        for (int kk = 0; kk < 9; ++kk) hb[kk] = bfbits(f[kk]);
        #pragma unroll
        for (int j = 0; j < 4; ++j) H[j] = hb[2*j] | (hb[2*j+1] << 16);
        H[4] = hb[8];
    }
    __syncthreads();                                             // B2

    // ---- layer 0 MFMA: wave w owns particles [w*64, w*64+64) x 128 cols ----
    {
        float pooled[8];
        #pragma unroll
        for (int nt = 0; nt < 8; ++nt) pooled[nt] = 0.0f;

        #pragma unroll
        for (int mt = 0; mt < 4; ++mt) {
            // wave transpose: pull packed hi-features from src lane mt*16+lm
            const int src = mt*16 + lm;
            const unsigned int t0 = (unsigned int)__shfl((int)H[0], src);
            const unsigned int t1 = (unsigned int)__shfl((int)H[1], src);
            const unsigned int t2 = (unsigned int)__shfl((int)H[2], src);
            const unsigned int t3 = (unsigned int)__shfl((int)H[3], src);
            const unsigned int t4 = (unsigned int)__shfl((int)H[4], src);

            // A-frag: even quads (k0..7 / k16..23) = f0..7; odd quads = [f8,0,0,0]
            union { unsigned int u[4]; bf16x8 v; } a;
            const bool evenq = ((quad & 1) == 0);
            a.u[0] = evenq ? t0 : t4;
            a.u[1] = evenq ? t1 : 0u;
            a.u[2] = evenq ? t2 : 0u;
            a.u[3] = evenq ? t3 : 0u;
            const bf16x8 af = a.v;

            #pragma unroll
            for (int nt = 0; nt < 8; ++nt) {
                const bf16x8 bf = *reinterpret_cast<const bf16x8*>(
                    &Wt[(nt*16 + lm) * WROW + quad*8]);
                const float cl = cvec[nt*16 + lm];
                const f32x4 cin = {cl, cl, cl, cl};
                const f32x4 acc = __builtin_amdgcn_mfma_f32_16x16x32_bf16(af, bf, cin, 0, 0, 0);
                #pragma unroll
                for (int r = 0; r < 4; ++r)
                    pooled[nt] += fmaxf(acc[r], 0.01f*acc[r]);   // leaky_relu
            }
        }
        #pragma unroll
        for (int nt = 0; nt < 8; ++nt) {
            pooled[nt] += __shfl_xor(pooled[nt], 16);
            pooled[nt] += __shfl_xor(pooled[nt], 32);
        }
        if (lane < 16) {
            #pragma unroll
            for (int nt = 0; nt < 8; ++nt) {
                // column 127: zero weights + zero cvec -> pools exactly 0
                atomicAdd(&hvec[nt*16 + lane], pooled[nt] * inv_nd);  // ds_add_f32
            }
        }
    }
    __syncthreads();                                             // B3

    // ---- layer 1: split-K-2 over all 256 threads; merge via ds_add_f32 ----
    const int half = tid >> 7;       // 0/1: k-range
    const int j    = tid & 127;      // output column
    const int kb   = half * 64;
    {
        float a = 0.0f;
        #pragma unroll 16
        for (int k = 0; k < 64; ++k)
            a = fmaf(hvec[kb + k], W1[(kb + k)*HD + j], a);
        atomicAdd(&h1pre[j], a);
    }
    __syncthreads();                                             // B4

    // ---- layer 2: split-K-2, leaky applied on-read; merge via ds_add_f32 ----
    {
        float a = 0.0f;
        #pragma unroll 16
        for (int k = 0; k < 64; ++k) {
            const float hk = h1pre[kb + k];
            const float lk = fmaxf(hk, 0.01f*hk);     // leaky(h1)
            a = fmaf(lk, W2[(kb + k)*HD + j], a);
        }
        atomicAdd(&outred[j], a);
    }
    __syncthreads();                                             // B5

    if (tid < HD)
        out[(long)bt * HD + tid] = outred[tid] / Pg[b];
}

extern "C" void kernel_launch(void* const* d_in, const int* in_sizes, int n_in,
                              void* d_out, int out_size, void* d_ws, size_t ws_size,
                              hipStream_t stream) {
    const float* x0    = (const float*)d_in[0];
    const float* x     = (const float*)d_in[1];
    const int*   N     = (const int*)  d_in[2];
    const float* basis = (const float*)d_in[3];
    const float* v     = (const float*)d_in[4];
    const float* P200c = (const float*)d_in[5];
    const float* W0    = (const float*)d_in[6];
    const float* b0    = (const float*)d_in[7];
    const float* W1    = (const float*)d_in[8];
    const float* b1    = (const float*)d_in[9];
    const float* W2    = (const float*)d_in[10];
    const float* b2    = (const float*)d_in[11];
    float* out = (float*)d_out;

    const int B  = in_sizes[5];                 // P200c is [B]
    const int T  = in_sizes[2] / B;             // N is [B,T]
    const int ND = in_sizes[1] / (in_sizes[2] * 3);  // x is [B,T,ND,3]

    hipLaunchKernelGGL(net_fused, dim3(B * T), dim3(256), 0, stream,
                       x0, x, N, basis, v, P200c, W0, b0, W1, b1, W2, b2,
                       out, T, ND);
}

// Round 15
// 109.505 us; speedup vs baseline: 1.0478x; 1.0478x over previous
//
#include <hip/hip_runtime.h>
#include <hip/hip_bf16.h>
#include <math.h>

#define EPSV 1e-5f
#define HD   128
#define WROW 40   // Wt bf16 row stride: 80B = 5 quartets, gcd(5,8)=1 -> balanced

typedef __attribute__((ext_vector_type(8))) short bf16x8;   // 8 bf16 = 4 VGPRs
typedef __attribute__((ext_vector_type(4))) float f32x4;

static __device__ __forceinline__ unsigned int bfbits(float x) {
    __hip_bfloat16 h = __float2bfloat16(x);
    unsigned short u;
    __builtin_memcpy(&u, &h, 2);
    return (unsigned int)u;
}

// FINAL (= R13, measured best: 108.8us total / kernel ~33us).
// One block per (b,t). blockDim = 256 = ND. 4 waves. Single dispatch.
// Design ledger (all measured on MI355X):
//  - Single dispatch: each extra dispatch ~6-10us fixed (R7).
//  - __launch_bounds__(256,4): (256,6) clamps allocator to 40 VGPR and
//    spills MFMA operands to scratch (R11/R12: FETCH 62MB, WRITE 119MB).
//  - Layer 0 via one mfma_f32_16x16x32_bf16 per (mt,nt): B rows hold
//    [whi k0..8 | wlo k16..24], A-hi duplicated in both k-halves
//    => exact ahi*(whi+wlo). A-side lo dropped: varying-feature bf16 noise
//    averages over the 256 pooled particles (R12/R13 absmax 0.0078).
//  - 10 per-(b,t)-constant features (W0 rows 4..13) exact fp32 via cvec,
//    folded into the MFMA accumulator init (bf16 error there is systematic
//    across the pool and broke the threshold in R3/R4).
//  - Feature transpose in-register (5 shfl/tile) -- no LDS staging buffer
//    (R5's scalar b16 LDS writes cost 1.57M bank-conflict cycles; R10's
//    2-halo LDS reuse doubled the serial critical path).
//  - Tail GEMVs: 128 threads, full-K, plain fmaf chain. Split-K-2 with LDS
//    atomics regressed +6us (R14) -- atomic drain + collisions beat the
//    halved load chain. Pool merge via ds_add_f32 into hvec is a win (R9).
__global__ __launch_bounds__(256, 4) void net_fused(
    const float* __restrict__ x0g, const float* __restrict__ xg,
    const int*   __restrict__ Ng,  const float* __restrict__ basisg,
    const float* __restrict__ vg,  const float* __restrict__ Pg,
    const float* __restrict__ W0,  const float* __restrict__ b0,
    const float* __restrict__ W1,  const float* __restrict__ b1,
    const float* __restrict__ W2,  const float* __restrict__ b2,
    float* __restrict__ out, int Tn, int NDn)
{
    __shared__ __align__(16) __hip_bfloat16 Wt[128 * WROW];  // [whi|wlo] rows
    __shared__ float cvec[HD];        // exact constant-feature contribution
    __shared__ float hvec[HD];        // pooled (atomic-accumulated) + logN
    __shared__ float h1vec[HD];       // layer-1 activations
    __shared__ float vred[4][3];      // v-mean wave partials

    const int bt   = blockIdx.x;
    const int b    = bt / Tn;
    const int tid  = threadIdx.x;
    const int lane = tid & 63;
    const int wave = tid >> 6;
    const int quad = lane >> 4;
    const int lm   = lane & 15;

    // ---- per-particle global loads (particle i = tid) ----
    const long pbase = ((long)bt * NDn + tid) * 3;
    const float xi0 = xg[pbase+0], xi1 = xg[pbase+1], xi2 = xg[pbase+2];
    const float vi0 = vg[pbase+0], vi1 = vg[pbase+1], vi2 = vg[pbase+2];

    // ---- v0 mean: wave shuffle reduce -> vred ----
    float s0 = vi0, s1 = vi1, s2 = vi2;
    #pragma unroll
    for (int off = 32; off > 0; off >>= 1) {
        s0 += __shfl_down(s0, off);
        s1 += __shfl_down(s1, off);
        s2 += __shfl_down(s2, off);
    }
    if (lane == 0) { vred[wave][0] = s0; vred[wave][1] = s1; vred[wave][2] = s2; }

    // ---- Wt staging by threads 0..127: row n = [whi k0..8 | wlo k16..24] ----
    if (tid < 128) {
        const int RV[9] = {0, 1, 2, 3, 14, 15, 16, 17, 18};
        __hip_bfloat16 r1[32];
        #pragma unroll
        for (int kk = 0; kk < 32; ++kk) r1[kk] = __float2bfloat16(0.0f);
        if (tid < 127) {
            #pragma unroll
            for (int kk = 0; kk < 9; ++kk) {
                const float wv = W0[RV[kk] * 127 + tid];   // coalesced across tid
                const __hip_bfloat16 hi = __float2bfloat16(wv);
                r1[kk]      = hi;                                          // whi
                r1[16 + kk] = __float2bfloat16(wv - __bfloat162float(hi)); // wlo
            }
        }
        bf16x8* d1 = reinterpret_cast<bf16x8*>(&Wt[tid * WROW]);
        const bf16x8* s1v = reinterpret_cast<const bf16x8*>(r1);
        d1[0] = s1v[0]; d1[1] = s1v[1]; d1[2] = s1v[2]; d1[3] = s1v[3];
    }
    __syncthreads();                                             // B1

    const float inv_nd = 1.0f / (float)NDn;
    const float v00 = (vred[0][0]+vred[1][0]+vred[2][0]+vred[3][0]) * inv_nd;
    const float v01 = (vred[0][1]+vred[1][1]+vred[2][1]+vred[3][1]) * inv_nd;
    const float v02 = (vred[0][2]+vred[1][2]+vred[2][2]+vred[3][2]) * inv_nd;

    // ---- per-(b,t) scalars ----
    const float p0 = x0g[bt*3+0], p1 = x0g[bt*3+1], p2 = x0g[bt*3+2];
    float bas[3][3];
    #pragma unroll
    for (int k = 0; k < 3; ++k)
        #pragma unroll
        for (int c = 0; c < 3; ++c)
            bas[k][c] = basisg[(b*3 + k)*3 + c];

    const float x0n  = sqrtf(p0*p0 + p1*p1 + p2*p2) + EPSV;
    const float ix0n = 1.0f / x0n;
    const float x0u0 = p0*ix0n, x0u1 = p1*ix0n, x0u2 = p2*ix0n;

    const float v0n  = sqrtf(v00*v00 + v01*v01 + v02*v02) + EPSV;
    const float iv0n = 1.0f / v0n;
    const float v0u0 = v00*iv0n, v0u1 = v01*iv0n, v0u2 = v02*iv0n;

    const float logN = log1pf((float)Ng[bt]);

    // ---- exact fp32 constant-feature contribution + hvec init ----
    if (tid < 128) {
        float c = 0.0f;
        if (tid < 127) {
            float fc[10];
            fc[0] = logN;
            fc[1] = x0n;
            fc[2] = x0u0*bas[0][0] + x0u1*bas[0][1] + x0u2*bas[0][2];
            fc[3] = x0u0*bas[1][0] + x0u1*bas[1][1] + x0u2*bas[1][2];
            fc[4] = x0u0*bas[2][0] + x0u1*bas[2][1] + x0u2*bas[2][2];
            fc[5] = v0n;
            fc[6] = v0u0*bas[0][0] + v0u1*bas[0][1] + v0u2*bas[0][2];
            fc[7] = v0u0*bas[1][0] + v0u1*bas[1][1] + v0u2*bas[1][2];
            fc[8] = v0u0*bas[2][0] + v0u1*bas[2][1] + v0u2*bas[2][2];
            fc[9] = x0u0*v0u0 + x0u1*v0u1 + x0u2*v0u2;
            c = b0[tid];
            #pragma unroll
            for (int i = 0; i < 10; ++i)
                c = fmaf(fc[i], W0[(4 + i) * 127 + tid], c);
        }
        cvec[tid] = c;
        hvec[tid] = (tid == 127) ? logN : 0.0f;   // atomic-accumulation base
    }

    // ---- varying features -> packed bf16-hi registers H[5] (no LDS, no lo) ----
    unsigned int H[5];
    {
        const float xn  = sqrtf(xi0*xi0 + xi1*xi1 + xi2*xi2) + EPSV;
        const float ixn = 1.0f / xn;
        const float xu0 = xi0*ixn, xu1 = xi1*ixn, xu2 = xi2*ixn;

        const float c0 = vi0 - v00, c1 = vi1 - v01, c2 = vi2 - v02;
        const float vn  = sqrtf(c0*c0 + c1*c1 + c2*c2) + EPSV;
        const float ivn = 1.0f / vn;
        const float vu0 = c0*ivn, vu1 = c1*ivn, vu2 = c2*ivn;

        float f[9];
        f[0] = xn;                                            // W0 row 0
        f[1] = xu0*bas[0][0] + xu1*bas[0][1] + xu2*bas[0][2]; // row 1
        f[2] = xu0*bas[1][0] + xu1*bas[1][1] + xu2*bas[1][2]; // row 2
        f[3] = xu0*bas[2][0] + xu1*bas[2][1] + xu2*bas[2][2]; // row 3
        f[4] = vn;                                            // row 14
        f[5] = vu0*bas[0][0] + vu1*bas[0][1] + vu2*bas[0][2]; // row 15
        f[6] = vu0*bas[1][0] + vu1*bas[1][1] + vu2*bas[1][2]; // row 16
        f[7] = vu0*bas[2][0] + vu1*bas[2][1] + vu2*bas[2][2]; // row 17
        f[8] = xu0*vu0 + xu1*vu1 + xu2*vu2;                   // row 18

        unsigned int hb[9];
        #pragma unroll
        for (int kk = 0; kk < 9; ++kk) hb[kk] = bfbits(f[kk]);
        #pragma unroll
        for (int j = 0; j < 4; ++j) H[j] = hb[2*j] | (hb[2*j+1] << 16);
        H[4] = hb[8];
    }
    __syncthreads();                                             // B2

    // ---- layer 0 MFMA: wave w owns particles [w*64, w*64+64) x 128 cols ----
    {
        float pooled[8];
        #pragma unroll
        for (int nt = 0; nt < 8; ++nt) pooled[nt] = 0.0f;

        #pragma unroll
        for (int mt = 0; mt < 4; ++mt) {
            // wave transpose: pull packed hi-features from src lane mt*16+lm
            const int src = mt*16 + lm;
            const unsigned int t0 = (unsigned int)__shfl((int)H[0], src);
            const unsigned int t1 = (unsigned int)__shfl((int)H[1], src);
            const unsigned int t2 = (unsigned int)__shfl((int)H[2], src);
            const unsigned int t3 = (unsigned int)__shfl((int)H[3], src);
            const unsigned int t4 = (unsigned int)__shfl((int)H[4], src);

            // A-frag: even quads (k0..7 / k16..23) = f0..7; odd quads = [f8,0,0,0]
            union { unsigned int u[4]; bf16x8 v; } a;
            const bool evenq = ((quad & 1) == 0);
            a.u[0] = evenq ? t0 : t4;
            a.u[1] = evenq ? t1 : 0u;
            a.u[2] = evenq ? t2 : 0u;
            a.u[3] = evenq ? t3 : 0u;
            const bf16x8 af = a.v;

            #pragma unroll
            for (int nt = 0; nt < 8; ++nt) {
                const bf16x8 bf = *reinterpret_cast<const bf16x8*>(
                    &Wt[(nt*16 + lm) * WROW + quad*8]);
                const float cl = cvec[nt*16 + lm];
                const f32x4 cin = {cl, cl, cl, cl};
                const f32x4 acc = __builtin_amdgcn_mfma_f32_16x16x32_bf16(af, bf, cin, 0, 0, 0);
                #pragma unroll
                for (int r = 0; r < 4; ++r)
                    pooled[nt] += fmaxf(acc[r], 0.01f*acc[r]);   // leaky_relu
            }
        }
        #pragma unroll
        for (int nt = 0; nt < 8; ++nt) {
            pooled[nt] += __shfl_xor(pooled[nt], 16);
            pooled[nt] += __shfl_xor(pooled[nt], 32);
        }
        if (lane < 16) {
            #pragma unroll
            for (int nt = 0; nt < 8; ++nt) {
                // column 127: zero weights + zero cvec -> pools exactly 0
                atomicAdd(&hvec[nt*16 + lane], pooled[nt] * inv_nd);  // ds_add_f32
            }
        }
    }
    __syncthreads();                                             // B3

    // ---- layer 1: thread j full-K GEMV; W loads coalesced across j ----
    if (tid < HD) {
        float a = b1[tid];
        #pragma unroll 16
        for (int k = 0; k < HD; ++k)
            a = fmaf(hvec[k], W1[k*HD + tid], a);
        h1vec[tid] = fmaxf(a, 0.01f*a);
    }
    __syncthreads();                                             // B4

    // ---- layer 2 + output scale ----
    if (tid < HD) {
        float a = b2[tid];
        #pragma unroll 16
        for (int k = 0; k < HD; ++k)
            a = fmaf(h1vec[k], W2[k*HD + tid], a);
        out[(long)bt * HD + tid] = a / Pg[b];
    }
}

extern "C" void kernel_launch(void* const* d_in, const int* in_sizes, int n_in,
                              void* d_out, int out_size, void* d_ws, size_t ws_size,
                              hipStream_t stream) {
    const float* x0    = (const float*)d_in[0];
    const float* x     = (const float*)d_in[1];
    const int*   N     = (const int*)  d_in[2];
    const float* basis = (const float*)d_in[3];
    const float* v     = (const float*)d_in[4];
    const float* P200c = (const float*)d_in[5];
    const float* W0    = (const float*)d_in[6];
    const float* b0    = (const float*)d_in[7];
    const float* W1    = (const float*)d_in[8];
    const float* b1    = (const float*)d_in[9];
    const float* W2    = (const float*)d_in[10];
    const float* b2    = (const float*)d_in[11];
    float* out = (float*)d_out;

    const int B  = in_sizes[5];                 // P200c is [B]
    const int T  = in_sizes[2] / B;             // N is [B,T]
    const int ND = in_sizes[1] / (in_sizes[2] * 3);  // x is [B,T,ND,3]

    hipLaunchKernelGGL(net_fused, dim3(B * T), dim3(256), 0, stream,
                       x0, x, N, basis, v, P200c, W0, b0, W1, b1, W2, b2,
                       out, T, ND);
}